// Round 7
// baseline (203.246 us; speedup 1.0000x reference)
//
#include <hip/hip_runtime.h>
#include <math.h>

#define EPS 1e-5f
#define NBATCH 8
#define NPTS 2048
#define KNB 16
#define BIG 3.2e38f

#define CHUNK_PTS 32
#define KNN_BLKS (NBATCH * 64)    // 64 chunks of 32 sorted-rank points per batch
#define THREADS 512
#define HALF 384                  // rank half-window; exactness enforced by edge check
#define WMAX 832                  // block window capacity (32 span + 768 + slack)
#define FUSED_LDS 38304

// ---- workspace layout (in floats) ----
#define WS_PRE 0                             // 16384*24 = 393216
#define WS_AUX 393216                        // 16384*72 = 1179648
#define WS_IDX 1572864                       // 16384*16 ints
#define WS_SX4 1835008                       // 8*2048*4 floats (sorted -2x,-2y,-2z,sq)
#define WS_SID 1900544                       // 8*2048 ints (sorted pos -> orig idx)

// Stored candidate = (-2x,-2y,-2z,sq). me* are RAW query coords.
// MUST be bitwise identical in scan and rescan.
__device__ __forceinline__ float dist2f(float mex, float mey, float mez, float sqn,
                                        float qx, float qy, float qz, float qw) {
  return fmaf(mex, qx, fmaf(mey, qy, fmaf(mez, qz, __fadd_rn(sqn, qw))));
}

__device__ __forceinline__ void sort16(float S[16]) {
#pragma unroll
  for (int pw = 1; pw < 16; pw <<= 1) {
#pragma unroll
    for (int k = pw; k >= 1; k >>= 1) {
#pragma unroll
      for (int j = (k & (pw - 1)); j + k < 16; j += 2 * k) {
#pragma unroll
        for (int i = 0; i < k; ++i) {
          int a = i + j, bq = i + j + k;
          if (bq < 16 && (a / (2 * pw) == bq / (2 * pw))) {
            float lo = fminf(S[a], S[bq]);
            float hi = fmaxf(S[a], S[bq]);
            S[a] = lo; S[bq] = hi;
          }
        }
      }
    }
  }
}

__device__ __forceinline__ void clean16(float m[16]) {
#pragma unroll
  for (int d = 8; d >= 1; d >>= 1) {
#pragma unroll
    for (int i = 0; i < 16; ++i) {
      if (!(i & d)) {
        float lo = fminf(m[i], m[i | d]);
        float hi = fmaxf(m[i], m[i | d]);
        m[i] = lo; m[i | d] = hi;
      }
    }
  }
}

// keep-16-smallest of sorted L and sorted S
__device__ __forceinline__ void merge16(float L[16], const float S[16]) {
  float m[16];
#pragma unroll
  for (int i = 0; i < 16; ++i) m[i] = fminf(L[i], S[15 - i]);
  clean16(m);
#pragma unroll
  for (int i = 0; i < 16; ++i) L[i] = m[i];
}

__device__ __forceinline__ void shflmerge16(float L[16], int mask) {
  float bb[16], m[16];
#pragma unroll
  for (int i = 0; i < 16; ++i) bb[i] = __shfl_xor(L[i], mask, 64);
#pragma unroll
  for (int i = 0; i < 16; ++i) m[i] = fminf(L[i], bb[15 - i]);
  clean16(m);
#pragma unroll
  for (int i = 0; i < 16; ++i) L[i] = m[i];
}

// ---- Kernel 0: per-batch bitonic sort by x; emit sorted float4 + orig idx ----
__global__ __launch_bounds__(1024) void sort_kernel(
    const float* __restrict__ x, float* __restrict__ sx4g, int* __restrict__ sidxg) {
  __shared__ float kx[NPTS];
  __shared__ int ki[NPTS];
  int b = blockIdx.x, tid = threadIdx.x;
  const float* xb = x + (size_t)b * 3 * NPTS;
  for (int j = tid; j < NPTS; j += 1024) { kx[j] = xb[j]; ki[j] = j; }
  __syncthreads();
  for (int k = 2; k <= NPTS; k <<= 1) {
    for (int j = k >> 1; j > 0; j >>= 1) {
      int t = 2 * tid - (tid & (j - 1));
      int t2 = t | j;
      bool up = ((t & k) == 0);
      float a = kx[t], c = kx[t2];
      int ia = ki[t], ic = ki[t2];
      bool sw = up ? (a > c) : (a < c);
      if (sw) { kx[t] = c; kx[t2] = a; ki[t] = ic; ki[t2] = ia; }
      __syncthreads();
    }
  }
  for (int j = tid; j < NPTS; j += 1024) {
    int n = ki[j];
    float xx = kx[j], yy = xb[NPTS + n], zz = xb[2 * NPTS + n];
    float sq = __fadd_rn(__fadd_rn(__fmul_rn(xx, xx), __fmul_rn(yy, yy)),
                         __fmul_rn(zz, zz));   // EXACT same formula as always
    ((float4*)sx4g)[(b << 11) + j] = make_float4(-2.0f * xx, -2.0f * yy, -2.0f * zz, sq);
    sidxg[(b << 11) + j] = n;
  }
}

// ---- Main kernel: 32 sorted-rank points; pre+aux + windowed exact 16-NN ----
__global__ __launch_bounds__(THREADS, 6) void fused_kernel(
    const float* __restrict__ x,
    const float* __restrict__ w_pre, const float* __restrict__ b_pre,
    const float* __restrict__ g_pre, const float* __restrict__ be_pre,
    const float* __restrict__ m_pre, const float* __restrict__ v_pre,
    const float* __restrict__ w1, const float* __restrict__ g1,
    const float* __restrict__ be1, const float* __restrict__ m1,
    const float* __restrict__ v1,
    const float* __restrict__ w2, const float* __restrict__ g2,
    const float* __restrict__ be2, const float* __restrict__ m2,
    const float* __restrict__ v2, const float* __restrict__ w3,
    const float* __restrict__ sx4g, const int* __restrict__ sidxg,
    float* __restrict__ pre, float* __restrict__ aux,
    int* __restrict__ knn_out) {
  extern __shared__ char smem[];
  float2* Wxy = (float2*)smem;               // [WMAX] (-2x,-2y)      6656 B
  float2* Wzs = (float2*)(smem + 6656);      // [WMAX] (-2z,sq)       6656 B
  int*   Widx = (int*)(smem + 13312);        // [WMAX] orig idx       3328 B
  // [16640, 33024): time-shared — weights (Step A/B) then slist (Step C)
  float* fwp   = (float*)(smem + 16640);     // 72
  float* fbp   = fwp + 72;                   // 24
  float* fw1t  = fbp + 24;                   // 576
  float* fb1   = fw1t + 576;                 // 12
  float* fw2t  = fb1 + 12;                   // 720
  float* fb2   = fw2t + 720;                 // 12
  float* fw3t  = fb2 + 12;                   // 576
  float* sinv1 = fw3t + 576;                 // 12
  float* sinv2 = sinv1 + 12;                 // 12
  float* sinvP = sinv2 + 12;                 // 24  (2040 total)
  float* slist = (float*)(smem + 16640);     // [8][16][32] = 4096 floats
  float* sd2   = (float*)(smem + 33024);     // [32][20]
  int*   sidxT = (int*)(smem + 35584);       // [32][20]
  int*   scnt  = (int*)(smem + 38144);       // [32]
  int*   sflag = (int*)(smem + 38272);       // 1

  int tid = threadIdx.x;
  int bi = blockIdx.x;
  int b = bi >> 6, chunk = bi & 63;
  int bq = b << 11;
  int vlo = chunk * CHUNK_PTS - HALF;        // window base (may be negative)
  const float* xb = x + (size_t)b * 3 * NPTS;
  const float4* sx4 = (const float4*)sx4g;

  // ---- Step A: stage window (SoA), BN inverses, zero tie bufs ----
  for (int idx = tid; idx < WMAX; idx += THREADS) {
    int g = vlo + idx;
    if ((unsigned)g < (unsigned)NPTS) {
      float4 f = sx4[bq + g];
      Wxy[idx] = make_float2(f.x, f.y);
      Wzs[idx] = make_float2(f.z, f.w);
      Widx[idx] = sidxg[bq + g];
    } else {
      Wxy[idx] = make_float2(0.f, 0.f);
      Wzs[idx] = make_float2(0.f, BIG);      // d2 -> ~BIG, auto-excluded
      Widx[idx] = 0;
    }
  }
  for (int j = tid; j < 32 * 20; j += THREADS) sidxT[j] = 0;
  if (tid < 32) scnt[tid] = 0;
  if (tid == 32) *sflag = 0;
  if (tid < 24) sinvP[tid] = g_pre[tid] / sqrtf(v_pre[tid] + EPS);
  if (tid < 12) { sinv1[tid] = g1[tid] / sqrtf(v1[tid] + EPS);
                  sinv2[tid] = g2[tid] / sqrtf(v2[tid] + EPS); }
  __syncthreads();
  if (tid < 72) fwp[tid] = w_pre[tid] * sinvP[tid / 3];
  if (tid < 24) fbp[tid] = (b_pre[tid] - m_pre[tid]) * sinvP[tid] + be_pre[tid];
  if (tid < 12) { fb1[tid] = be1[tid] - m1[tid] * sinv1[tid];
                  fb2[tid] = be2[tid] - m2[tid] * sinv2[tid]; }
  for (int j = tid; j < 576; j += THREADS) { int i = j / 12, o = j - i * 12; fw1t[j] = w1[o * 48 + i] * sinv1[o]; }
  for (int j = tid; j < 720; j += THREADS) { int i = j / 12, o = j - i * 12; fw2t[j] = w2[o * 60 + i] * sinv2[o]; }
  for (int j = tid; j < 576; j += THREADS) { int i = j / 12, o = j - i * 12; fw3t[j] = w3[o * 72 + 24 + i]; }
  __syncthreads();

  // ---- Step B: pre + aux for the block's 32 points (orig idx via sidxg) ----
  {
    int r = tid & 15, pt = tid >> 4;
    int n0 = sidxg[bq + chunk * CHUNK_PTS + pt];
    size_t pgl = (size_t)bq + n0;
    float x0 = xb[n0], x1 = xb[NPTS + n0], x2 = xb[2 * NPTS + n0];
    float pr[24];
#pragma unroll
    for (int c = 0; c < 24; ++c) {
      float v = fmaf(fwp[c * 3 + 0], x0,
                fmaf(fwp[c * 3 + 1], x1,
                fmaf(fwp[c * 3 + 2], x2, fbp[c])));
      pr[c] = fmaxf(v, 0.f);
    }
    if (r == 12) {
      float4* o4 = (float4*)(pre + pgl * 24);
#pragma unroll
      for (int i = 0; i < 6; ++i)
        o4[i] = make_float4(pr[4*i], pr[4*i+1], pr[4*i+2], pr[4*i+3]);
    }
    if (r < 12) {
      int o = r;
      float u1 = fb1[o], a1 = 0.f, u2 = fb2[o], a2 = 0.f, u3 = 0.f, a3 = 0.f;
#pragma unroll
      for (int i = 0; i < 24; ++i) {
        u1 = fmaf(fw1t[i * 12 + o],        pr[i], u1);
        a1 = fmaf(fw1t[(24 + i) * 12 + o], pr[i], a1);
        u2 = fmaf(fw2t[(12 + i) * 12 + o], pr[i], u2);
        a2 = fmaf(fw2t[(36 + i) * 12 + o], pr[i], a2);
        u3 = fmaf(fw3t[i * 12 + o],        pr[i], u3);
        a3 = fmaf(fw3t[(24 + i) * 12 + o], pr[i], a3);
      }
      float* A = aux + pgl * 72;
      A[o] = u1; A[12 + o] = u2; A[24 + o] = u3;
      A[36 + o] = a1; A[48 + o] = a2; A[60 + o] = a3;
    }
  }
  __syncthreads();   // weights dead; slist region live from here

  // ---- Step C: windowed exact 16-NN ----
  int p = tid & 31, s = tid >> 5;            // point 0..31, window-slice 0..15
  int q = chunk * CHUNK_PTS + p;             // sorted rank of query
  float2 mxy = Wxy[p + HALF], mzs = Wzs[p + HALF];   // self (g==q)
  float mex = -0.5f * mxy.x, mey = -0.5f * mxy.y, mez = -0.5f * mzs.x;
  float sqn = mzs.y;
  // Phase 1: 3 batches of 16 per lane over window offsets s*16 + t*256 + cc
  float L[16];
#pragma unroll
  for (int t = 0; t < 16; ++t) L[t] = BIG;
#pragma unroll
  for (int t = 0; t < 3; ++t) {
    float S[16];
#pragma unroll
    for (int cc = 0; cc < 16; ++cc) {
      int idx = p + s * 16 + t * 256 + cc;
      float2 a = Wxy[idx], z = Wzs[idx];
      float d2 = dist2f(mex, mey, mez, sqn, a.x, a.y, z.x, z.y);
      if (t * 256 + cc == 256) d2 = (s == 8) ? BIG : d2;   // self at off 384
      S[cc] = d2;
    }
    sort16(S);
    merge16(L, S);
  }
  // in-wave merge of the wave's two slices, then 8 lists -> LDS tree
  shflmerge16(L, 32);
  if (!(s & 1)) {
    int w = tid >> 6;
#pragma unroll
    for (int i = 0; i < 16; ++i) slist[(w * 16 + i) * 32 + p] = L[i];
  }
  __syncthreads();
  for (int W = 4; W >= 1; W >>= 1) {
    int u = tid >> 5;
    bool act = (u < W);
    float a[16], bb[16];
    if (act) {
#pragma unroll
      for (int i = 0; i < 16; ++i) a[i]  = slist[((2 * u) * 16 + i) * 32 + p];
#pragma unroll
      for (int i = 0; i < 16; ++i) bb[i] = slist[((2 * u + 1) * 16 + i) * 32 + p];
    }
    __syncthreads();
    if (act) {
      float m[16];
#pragma unroll
      for (int i = 0; i < 16; ++i) m[i] = fminf(a[i], bb[15 - i]);
      clean16(m);
#pragma unroll
      for (int i = 0; i < 16; ++i) slist[(u * 16 + i) * 32 + p] = m[i];
    }
    __syncthreads();
  }
  float tau = slist[15 * 32 + p];            // exact 16th within window
  // Edge check: any unscanned rank could beat tau? (dx^2 lower-bounds d2)
  if (tid < 32) {
    int qq = chunk * CHUNK_PTS + tid;
    float xq = -0.5f * Wxy[tid + HALF].x;
    float tt = slist[15 * 32 + tid];
    bool bad = false;
    int gl = qq - HALF - 1;
    if (gl >= 0) { float xe = -0.5f * sx4[bq + gl].x; float dx = xe - xq; if (dx * dx <= tt) bad = true; }
    int gr = qq + HALF;
    if (gr < NPTS) { float xe = -0.5f * sx4[bq + gr].x; float dx = xe - xq; if (dx * dx <= tt) bad = true; }
    if (bad) atomicOr(sflag, 1);
  }
  __syncthreads();
  int flag = *sflag;

  if (!flag) {
    // Phase 3: window rescan, collect (d2, orig idx) with d2 <= tau
#pragma unroll
    for (int t = 0; t < 3; ++t) {
#pragma unroll
      for (int cc = 0; cc < 16; ++cc) {
        int idx = p + s * 16 + t * 256 + cc;
        float2 a = Wxy[idx], z = Wzs[idx];
        float d2 = dist2f(mex, mey, mez, sqn, a.x, a.y, z.x, z.y);
        bool self = (t * 256 + cc == 256) && (s == 8);
        if (!self && d2 <= tau) {
          int pos = atomicAdd(&scnt[p], 1);
          if (pos < 20) { sd2[p * 20 + pos] = d2; sidxT[p * 20 + pos] = Widx[idx]; }
        }
      }
    }
  } else {
    // Fallback (rare, block-uniform): exact full-2048 scan from global sorted array
    const float4* Cg = sx4 + bq + s * 128;
    float L2[16];
#pragma unroll
    for (int t = 0; t < 16; ++t) L2[t] = BIG;
    for (int c0 = 0; c0 < 128; c0 += 16) {
      float S[16];
#pragma unroll
      for (int cc = 0; cc < 16; ++cc) {
        float4 f = Cg[c0 + cc];
        float d2 = dist2f(mex, mey, mez, sqn, f.x, f.y, f.z, f.w);
        int gg = s * 128 + c0 + cc;
        S[cc] = (gg == q) ? BIG : d2;
      }
      sort16(S);
      merge16(L2, S);
    }
    shflmerge16(L2, 32);
    if (!(s & 1)) {
      int w = tid >> 6;
#pragma unroll
      for (int i = 0; i < 16; ++i) slist[(w * 16 + i) * 32 + p] = L2[i];
    }
    __syncthreads();
    for (int W = 4; W >= 1; W >>= 1) {
      int u = tid >> 5;
      bool act = (u < W);
      float a[16], bb[16];
      if (act) {
#pragma unroll
        for (int i = 0; i < 16; ++i) a[i]  = slist[((2 * u) * 16 + i) * 32 + p];
#pragma unroll
        for (int i = 0; i < 16; ++i) bb[i] = slist[((2 * u + 1) * 16 + i) * 32 + p];
      }
      __syncthreads();
      if (act) {
        float m[16];
#pragma unroll
        for (int i = 0; i < 16; ++i) m[i] = fminf(a[i], bb[15 - i]);
        clean16(m);
#pragma unroll
        for (int i = 0; i < 16; ++i) slist[(u * 16 + i) * 32 + p] = m[i];
      }
      __syncthreads();
    }
    float tau2 = slist[15 * 32 + p];
    for (int c = 0; c < 128; ++c) {
      float4 f = Cg[c];
      float d2 = dist2f(mex, mey, mez, sqn, f.x, f.y, f.z, f.w);
      int gg = s * 128 + c;
      if (gg != q && d2 <= tau2) {
        int pos = atomicAdd(&scnt[p], 1);
        if (pos < 20) { sd2[p * 20 + pos] = d2; sidxT[p * 20 + pos] = sidxg[bq + gg]; }
      }
    }
  }
  __syncthreads();
  // Phase 4: rare tie fixup — keep 16 smallest by (d2, idx) lexicographic
  if (tid < 32) {
    int c = scnt[tid]; if (c > 20) c = 20;
    if (c > 16) {
      for (int t = 0; t < 16; ++t) {
        int best = t;
        for (int u = t + 1; u < c; ++u) {
          float da = sd2[tid * 20 + u], db = sd2[tid * 20 + best];
          int ia = sidxT[tid * 20 + u], ib = sidxT[tid * 20 + best];
          if (da < db || (da == db && ia < ib)) best = u;
        }
        float td = sd2[tid * 20 + t]; sd2[tid * 20 + t] = sd2[tid * 20 + best]; sd2[tid * 20 + best] = td;
        int ti = sidxT[tid * 20 + t]; sidxT[tid * 20 + t] = sidxT[tid * 20 + best]; sidxT[tid * 20 + best] = ti;
      }
    }
  }
  __syncthreads();
  {
    int pp = tid >> 4, kk = tid & 15;        // 512 threads = 32 pts x 16 nbrs
    int n_orig = sidxg[bq + chunk * CHUNK_PTS + pp];
    knn_out[((size_t)b * NPTS + n_orig) * KNB + kk] = sidxT[pp * 20 + kk];
  }
}

// Fused edge-MLP + max. 16 lanes/point; neighbor-dependent 12x12 blocks only.
__global__ __launch_bounds__(256) void mlp_kernel(
    const float* __restrict__ pre, const float* __restrict__ aux,
    const int* __restrict__ knn, const float* __restrict__ x,
    const float* __restrict__ w2, const float* __restrict__ g2,
    const float* __restrict__ v2, const float* __restrict__ w3,
    float* __restrict__ out) {
  __shared__ float sW2h[144], sW3h2[144], sW3h1[144];
  __shared__ float sout[87 * 16];
  int tid = threadIdx.x;
  if (tid < 144) {
    int o = tid / 12, i = tid - o * 12;
    float inv2 = g2[o] / sqrtf(v2[o] + EPS);
    sW2h[tid]  = w2[o * 60 + i] * inv2;
    sW3h2[tid] = w3[o * 72 + i];
    sW3h1[tid] = w3[o * 72 + 12 + i];
  }
  __syncthreads();
  int k = tid & 15, pl = tid >> 4;
  int p = blockIdx.x * 16 + pl;            // 0..16383
  int b = p >> 11, n = p & (NPTS - 1);
  int nb = knn[(size_t)p * KNB + k];
  const float4* u4 = (const float4*)(aux + (size_t)p * 72);
  const float4* a4 = (const float4*)(aux + ((size_t)(b << 11) + nb) * 72 + 36);
  float uc[36], av[36];
#pragma unroll
  for (int i = 0; i < 9; ++i) {
    float4 t = u4[i];
    uc[4*i] = t.x; uc[4*i+1] = t.y; uc[4*i+2] = t.z; uc[4*i+3] = t.w;
    float4 t2 = a4[i];
    av[4*i] = t2.x; av[4*i+1] = t2.y; av[4*i+2] = t2.z; av[4*i+3] = t2.w;
  }
  float h1[12], h2[12], h3[12];
#pragma unroll
  for (int o = 0; o < 12; ++o) h1[o] = fmaxf(uc[o] + av[o], 0.f);
#pragma unroll
  for (int o = 0; o < 12; ++o) {
    float a = uc[12 + o] + av[12 + o];
#pragma unroll
    for (int i = 0; i < 12; ++i) a = fmaf(sW2h[o * 12 + i], h1[i], a);
    h2[o] = fmaxf(a, 0.f);
  }
#pragma unroll
  for (int o = 0; o < 12; ++o) {
    float a = uc[24 + o] + av[24 + o];
#pragma unroll
    for (int i = 0; i < 12; ++i) a = fmaf(sW3h2[o * 12 + i], h2[i], a);
#pragma unroll
    for (int i = 0; i < 12; ++i) a = fmaf(sW3h1[o * 12 + i], h1[i], a);
    h3[o] = a;
  }
  float nbf[24];
  const float4* pn4 = (const float4*)(pre + ((size_t)(b << 11) + nb) * 24);
#pragma unroll
  for (int i = 0; i < 6; ++i) {
    float4 t = pn4[i];
    nbf[4*i] = t.x; nbf[4*i+1] = t.y; nbf[4*i+2] = t.z; nbf[4*i+3] = t.w;
  }
#pragma unroll
  for (int m = 1; m < 16; m <<= 1) {
#pragma unroll
    for (int o = 0; o < 12; ++o) {
      h1[o] = fmaxf(h1[o], __shfl_xor(h1[o], m, 16));
      h2[o] = fmaxf(h2[o], __shfl_xor(h2[o], m, 16));
      h3[o] = fmaxf(h3[o], __shfl_xor(h3[o], m, 16));
    }
#pragma unroll
    for (int i = 0; i < 24; ++i)
      nbf[i] = fmaxf(nbf[i], __shfl_xor(nbf[i], m, 16));
  }
  if (k == 0) {
    const float4* c4 = (const float4*)(pre + (size_t)p * 24);
#pragma unroll
    for (int o = 0; o < 12; ++o) {
      sout[(0  + o) * 16 + pl] = h3[o];
      sout[(12 + o) * 16 + pl] = h2[o];
      sout[(24 + o) * 16 + pl] = h1[o];
    }
#pragma unroll
    for (int i = 0; i < 6; ++i) {
      float4 t = c4[i];
      sout[(36 + 4*i    ) * 16 + pl] = t.x;
      sout[(36 + 4*i + 1) * 16 + pl] = t.y;
      sout[(36 + 4*i + 2) * 16 + pl] = t.z;
      sout[(36 + 4*i + 3) * 16 + pl] = t.w;
    }
#pragma unroll
    for (int i = 0; i < 24; ++i) sout[(60 + i) * 16 + pl] = nbf[i];
    const float* xb = x + (size_t)b * 3 * NPTS + n;
    sout[84 * 16 + pl] = xb[0];
    sout[85 * 16 + pl] = xb[NPTS];
    sout[86 * 16 + pl] = xb[2 * NPTS];
  }
  __syncthreads();
  int n0 = (blockIdx.x * 16) & (NPTS - 1);
  float* ob = out + (size_t)b * 87 * NPTS;
  for (int j2 = tid; j2 < 87 * 16; j2 += 256) {
    int c = j2 >> 4, i = j2 & 15;
    ob[(size_t)c * NPTS + n0 + i] = sout[j2];
  }
}

extern "C" void kernel_launch(void* const* d_in, const int* in_sizes, int n_in,
                              void* d_out, int out_size, void* d_ws, size_t ws_size,
                              hipStream_t stream) {
  (void)in_sizes; (void)n_in; (void)out_size; (void)ws_size;
  const float* x     = (const float*)d_in[0];
  const float* w_pre = (const float*)d_in[1];
  const float* b_pre = (const float*)d_in[2];
  const float* g_pre = (const float*)d_in[3];
  const float* be_pre= (const float*)d_in[4];
  const float* m_pre = (const float*)d_in[5];
  const float* v_pre = (const float*)d_in[6];
  const float* w1    = (const float*)d_in[7];
  const float* g1    = (const float*)d_in[8];
  const float* be1   = (const float*)d_in[9];
  const float* m1    = (const float*)d_in[10];
  const float* v1    = (const float*)d_in[11];
  const float* w2    = (const float*)d_in[12];
  const float* g2    = (const float*)d_in[13];
  const float* be2   = (const float*)d_in[14];
  const float* m2    = (const float*)d_in[15];
  const float* v2    = (const float*)d_in[16];
  const float* w3    = (const float*)d_in[17];
  float* ws   = (float*)d_ws;
  float* pre  = ws + WS_PRE;
  float* aux  = ws + WS_AUX;
  int*   knn  = (int*)(ws + WS_IDX);
  float* sx4g = ws + WS_SX4;
  int*  sidxg = (int*)(ws + WS_SID);
  float* out  = (float*)d_out;

  sort_kernel<<<NBATCH, 1024, 0, stream>>>(x, sx4g, sidxg);
  fused_kernel<<<KNN_BLKS, THREADS, FUSED_LDS, stream>>>(
      x, w_pre, b_pre, g_pre, be_pre, m_pre, v_pre,
      w1, g1, be1, m1, v1, w2, g2, be2, m2, v2, w3,
      sx4g, sidxg, pre, aux, knn);
  mlp_kernel<<<NBATCH * NPTS / 16, 256, 0, stream>>>(pre, aux, knn, x,
                                                     w2, g2, v2, w3, out);
}

// Round 8
// 160.269 us; speedup vs baseline: 1.2682x; 1.2682x over previous
//
#include <hip/hip_runtime.h>
#include <math.h>

#define EPS 1e-5f
#define NBATCH 8
#define NPTS 2048
#define KNB 16
#define BIG 3.2e38f

#define CHUNK_PTS 32
#define KNN_BLKS (NBATCH * 64)    // 64 chunks of 32 points per batch = 512 blocks
#define THREADS 512
#define FUSED_LDS 49152           // 32KB C4 + 16KB time-shared

// ---- workspace layout (in floats) ----
#define WS_PRE 0                             // 16384*24
#define WS_AUX (16384 * 24)                  // 16384*72
#define WS_IDX (WS_AUX + 16384 * 72)         // 16384*16 ints
#define WS_C4G (WS_IDX + 16384 * 16)         // 16384 float4 (-2x,-2y,-2z,sq)

// Candidate = (-2x,-2y,-2z,sq). me* are RAW query coords (recovered exactly).
// MUST be bitwise identical in phase 1 (LDS copy) and phase 3 (global).
__device__ __forceinline__ float dist2f(float mex, float mey, float mez,
                                        float sqn, float4 q) {
  return fmaf(mex, q.x, fmaf(mey, q.y, fmaf(mez, q.z, __fadd_rn(sqn, q.w))));
}

// Phase-1 scan of one 128-candidate slice, merging into sorted L[16].
// HASSELF=false skips the per-candidate self mask (only 1 of 8 waves needs it).
template <bool HASSELF>
__device__ __forceinline__ void scan_slice(const float4* __restrict__ Cs, int selfc,
                                           float mex, float mey, float mez,
                                           float sqn, float L[16]) {
  for (int c0 = 0; c0 < 128; c0 += 16) {
    float S[16];
#pragma unroll
    for (int cc = 0; cc < 16; ++cc) {
      float4 q = Cs[c0 + cc];
      float d2 = dist2f(mex, mey, mez, sqn, q);
      if (HASSELF) S[cc] = ((c0 + cc) == selfc) ? BIG : d2;
      else         S[cc] = d2;
    }
    // Batcher odd-even mergesort, ascending (all indices compile-time)
#pragma unroll
    for (int pw = 1; pw < 16; pw <<= 1) {
#pragma unroll
      for (int k = pw; k >= 1; k >>= 1) {
#pragma unroll
        for (int j = (k & (pw - 1)); j + k < 16; j += 2 * k) {
#pragma unroll
          for (int i = 0; i < k; ++i) {
            int a = i + j, bq = i + j + k;
            if (bq < 16 && (a / (2 * pw) == bq / (2 * pw))) {
              float lo = fminf(S[a], S[bq]);
              float hi = fmaxf(S[a], S[bq]);
              S[a] = lo; S[bq] = hi;
            }
          }
        }
      }
    }
    // keep-16-smallest merge of sorted L and sorted S (bitonic lower half)
    float m[16];
#pragma unroll
    for (int i = 0; i < 16; ++i) m[i] = fminf(L[i], S[15 - i]);
#pragma unroll
    for (int d = 8; d >= 1; d >>= 1) {
#pragma unroll
      for (int i = 0; i < 16; ++i) {
        if (!(i & d)) {
          float lo = fminf(m[i], m[i | d]);
          float hi = fmaxf(m[i], m[i | d]);
          m[i] = lo; m[i | d] = hi;
        }
      }
    }
#pragma unroll
    for (int i = 0; i < 16; ++i) L[i] = m[i];
  }
}

// ---- Kernel 0: materialize C4 once in global (L2-resident, 256 KB total) ----
__global__ __launch_bounds__(256) void prep_kernel(
    const float* __restrict__ x, float4* __restrict__ c4g) {
  int i = blockIdx.x * 256 + threadIdx.x;     // 0..16383
  int b = i >> 11, n = i & (NPTS - 1);
  const float* xb = x + (size_t)b * 3 * NPTS;
  float xx = xb[n], yy = xb[NPTS + n], zz = xb[2 * NPTS + n];
  float sq = __fadd_rn(__fadd_rn(__fmul_rn(xx, xx), __fmul_rn(yy, yy)),
                       __fmul_rn(zz, zz));
  c4g[i] = make_float4(-2.0f * xx, -2.0f * yy, -2.0f * zz, sq);
}

// One uniform kernel: every block handles 32 points: pre+aux fold + exact 16-NN.
// 512 threads = 8 waves; each wave holds 2 slices of 128 (2-way broadcast = free).
// Phase 1 reads LDS (copy of c4g); phase 3 rescan reads GLOBAL c4g (same bits).
__global__ __launch_bounds__(THREADS, 6) void fused_kernel(
    const float* __restrict__ x,
    const float* __restrict__ w_pre, const float* __restrict__ b_pre,
    const float* __restrict__ g_pre, const float* __restrict__ be_pre,
    const float* __restrict__ m_pre, const float* __restrict__ v_pre,
    const float* __restrict__ w1, const float* __restrict__ g1,
    const float* __restrict__ be1, const float* __restrict__ m1,
    const float* __restrict__ v1,
    const float* __restrict__ w2, const float* __restrict__ g2,
    const float* __restrict__ be2, const float* __restrict__ m2,
    const float* __restrict__ v2, const float* __restrict__ w3,
    const float4* __restrict__ c4g,
    float* __restrict__ pre, float* __restrict__ aux,
    int* __restrict__ knn_out) {
  extern __shared__ char smem[];
  float4* C4   = (float4*)smem;              // [2048] copy of batch c4g, 32 KB
  float* slist = (float*)(smem + 32768);     // 4096 floats, 16 KB, time-shared:
  // life 1 (until Step-B barrier): folded weights, transposed for bank-free reads
  float* fwp   = slist;                      // 72   [o*3+c]
  float* fbp   = fwp + 72;                   // 24
  float* fw1t  = fbp + 24;                   // 576  [i*12+o] = w1[o*48+i]*inv1
  float* fb1   = fw1t + 576;                 // 12
  float* fw2t  = fb1 + 12;                   // 720  [i*12+o] = w2[o*60+i]*inv2
  float* fb2   = fw2t + 720;                 // 12
  float* fw3t  = fb2 + 12;                   // 576  [i*12+o] = w3[o*72+24+i]
  float* sinv1 = fw3t + 576;                 // 12
  float* sinv2 = sinv1 + 12;                 // 12
  float* sinvP = sinv2 + 12;                 // 24  (total 2040)
  // life 2 (phase 1/2): merge lists [8 lists][16 vals][32 pts] = 4096 floats
  // life 3 (after tau): tie buffers
  float* sd2  = slist;                       // [32][20]
  int*   sidx = (int*)(slist + 640);         // [32][20]
  int*   scnt = (int*)(slist + 1280);        // [32]

  int tid = threadIdx.x;
  int bi = blockIdx.x;
  int b = bi >> 6, chunk = bi & 63;
  int bq = b << 11;
  const float* xb = x + (size_t)b * 3 * NPTS;

  // ---- Step A: copy-stage C4 from c4g, precompute BN inverses ----
  for (int j = tid; j < NPTS; j += THREADS) C4[j] = c4g[bq + j];
  if (tid < 24) sinvP[tid] = g_pre[tid] / sqrtf(v_pre[tid] + EPS);
  if (tid < 12) { sinv1[tid] = g1[tid] / sqrtf(v1[tid] + EPS);
                  sinv2[tid] = g2[tid] / sqrtf(v2[tid] + EPS); }
  __syncthreads();
  if (tid < 72) fwp[tid] = w_pre[tid] * sinvP[tid / 3];
  if (tid < 24) fbp[tid] = (b_pre[tid] - m_pre[tid]) * sinvP[tid] + be_pre[tid];
  if (tid < 12) { fb1[tid] = be1[tid] - m1[tid] * sinv1[tid];
                  fb2[tid] = be2[tid] - m2[tid] * sinv2[tid]; }
  for (int j = tid; j < 576; j += THREADS) { int i = j / 12, o = j - i * 12; fw1t[j] = w1[o * 48 + i] * sinv1[o]; }
  for (int j = tid; j < 720; j += THREADS) { int i = j / 12, o = j - i * 12; fw2t[j] = w2[o * 60 + i] * sinv2[o]; }
  for (int j = tid; j < 576; j += THREADS) { int i = j / 12, o = j - i * 12; fw3t[j] = w3[o * 72 + 24 + i]; }
  __syncthreads();

  // ---- Step B: pre + aux for this block's 32 points (16 lanes/point) ----
  {
    int r = tid & 15, pt = tid >> 4;
    int n0 = chunk * CHUNK_PTS + pt;
    size_t pgl = (size_t)bq + n0;
    float x0 = xb[n0], x1 = xb[NPTS + n0], x2 = xb[2 * NPTS + n0];
    float pr[24];
#pragma unroll
    for (int c = 0; c < 24; ++c) {
      float v = fmaf(fwp[c * 3 + 0], x0,
                fmaf(fwp[c * 3 + 1], x1,
                fmaf(fwp[c * 3 + 2], x2, fbp[c])));
      pr[c] = fmaxf(v, 0.f);
    }
    if (r == 12) {   // pre writer on a lane disjoint from aux lanes
      float4* o4 = (float4*)(pre + pgl * 24);
#pragma unroll
      for (int i = 0; i < 6; ++i)
        o4[i] = make_float4(pr[4*i], pr[4*i+1], pr[4*i+2], pr[4*i+3]);
    }
    if (r < 12) {
      int o = r;
      float u1 = fb1[o], a1 = 0.f, u2 = fb2[o], a2 = 0.f, u3 = 0.f, a3 = 0.f;
#pragma unroll
      for (int i = 0; i < 24; ++i) {
        u1 = fmaf(fw1t[i * 12 + o],        pr[i], u1);
        a1 = fmaf(fw1t[(24 + i) * 12 + o], pr[i], a1);
        u2 = fmaf(fw2t[(12 + i) * 12 + o], pr[i], u2);
        a2 = fmaf(fw2t[(36 + i) * 12 + o], pr[i], a2);
        u3 = fmaf(fw3t[i * 12 + o],        pr[i], u3);
        a3 = fmaf(fw3t[(24 + i) * 12 + o], pr[i], a3);
      }
      float* A = aux + pgl * 72;
      A[o] = u1; A[12 + o] = u2; A[24 + o] = u3;
      A[36 + o] = a1; A[48 + o] = a2; A[60 + o] = a3;
    }
  }
  __syncthreads();   // folded-weight area dead; slist lists live from here

  // ---- Step C: exact 16-NN, 32 points x 16 slices of 128 candidates ----
  int p = tid & 31, s = tid >> 5;            // point 0..31, slice 0..15
  int w = tid >> 6;                          // wave 0..7 (slices 2w, 2w+1)
  int n = chunk * CHUNK_PTS + p;
  float4 me4 = C4[n];
  float mex = -0.5f * me4.x, mey = -0.5f * me4.y, mez = -0.5f * me4.z;
  float sqn = me4.w;
  const float4* Cs = C4 + s * 128;
  int selfc = n - s * 128;                   // in [0,128) only for self slice
  int wself = chunk >> 3;                    // wave whose slice pair holds the self slice
  // Phase 1: batched top-16; self mask only in the self wave
  float L[16];
#pragma unroll
  for (int t = 0; t < 16; ++t) L[t] = BIG;
  if (w == wself) scan_slice<true >(Cs, selfc, mex, mey, mez, sqn, L);
  else            scan_slice<false>(Cs, selfc, mex, mey, mez, sqn, L);
  // in-wave merge: the wave's two slices (lanes l and l^32 share point p)
  {
    float bb[16], m16[16];
#pragma unroll
    for (int i = 0; i < 16; ++i) bb[i] = __shfl_xor(L[i], 32, 64);
#pragma unroll
    for (int i = 0; i < 16; ++i) m16[i] = fminf(L[i], bb[15 - i]);
#pragma unroll
    for (int d = 8; d >= 1; d >>= 1) {
#pragma unroll
      for (int i = 0; i < 16; ++i) {
        if (!(i & d)) {
          float lo = fminf(m16[i], m16[i | d]);
          float hi = fmaxf(m16[i], m16[i | d]);
          m16[i] = lo; m16[i | d] = hi;
        }
      }
    }
    if (!(s & 1)) {                          // lanes 0..31 of each wave
#pragma unroll
      for (int i = 0; i < 16; ++i) slist[(w * 16 + i) * 32 + p] = m16[i];
    }
  }
  __syncthreads();
  // Phase 2: merge tree 8 -> 4 -> 2 -> 1 lists (parallel over points)
  for (int W = 4; W >= 1; W >>= 1) {
    int u = tid >> 5;
    bool act = (u < W);
    float a[16], bb[16];
    if (act) {
#pragma unroll
      for (int i = 0; i < 16; ++i) a[i]  = slist[((2 * u) * 16 + i) * 32 + p];
#pragma unroll
      for (int i = 0; i < 16; ++i) bb[i] = slist[((2 * u + 1) * 16 + i) * 32 + p];
    }
    __syncthreads();
    if (act) {
      float m16[16];
#pragma unroll
      for (int i = 0; i < 16; ++i) m16[i] = fminf(a[i], bb[15 - i]);
#pragma unroll
      for (int d = 8; d >= 1; d >>= 1) {
#pragma unroll
        for (int i = 0; i < 16; ++i) {
          if (!(i & d)) {
            float lo = fminf(m16[i], m16[i | d]);
            float hi = fmaxf(m16[i], m16[i | d]);
            m16[i] = lo; m16[i | d] = hi;
          }
        }
      }
#pragma unroll
      for (int i = 0; i < 16; ++i) slist[(u * 16 + i) * 32 + p] = m16[i];
    }
    __syncthreads();
  }
  float tau = slist[15 * 32 + p];            // exact 16th smallest (self excluded)
  __syncthreads();                           // everyone has tau; reuse slist region
  for (int j = tid; j < 32 * 20; j += THREADS) sidx[j] = 0;
  if (tid < 32) scnt[tid] = 0;
  __syncthreads();
  // Phase 3: rescan from GLOBAL c4g (bit-identical to LDS copy -> exact tau
  // semantics), collecting indices with d2 <= tau. Frees the LDS pipe.
  {
    const float4* Cg = c4g + bq + s * 128;
    if (w == wself) {
#pragma unroll 4
      for (int c = 0; c < 128; ++c) {
        float4 q = Cg[c];
        float d2 = dist2f(mex, mey, mez, sqn, q);
        int j = s * 128 + c;
        if (d2 <= tau && j != n) {
          int pos = atomicAdd(&scnt[p], 1);
          if (pos < 20) { sd2[p * 20 + pos] = d2; sidx[p * 20 + pos] = j; }
        }
      }
    } else {
#pragma unroll 4
      for (int c = 0; c < 128; ++c) {
        float4 q = Cg[c];
        float d2 = dist2f(mex, mey, mez, sqn, q);
        int j = s * 128 + c;
        if (d2 <= tau) {
          int pos = atomicAdd(&scnt[p], 1);
          if (pos < 20) { sd2[p * 20 + pos] = d2; sidx[p * 20 + pos] = j; }
        }
      }
    }
  }
  __syncthreads();
  // Phase 4: rare tie fixup — keep 16 smallest by (d2, idx) lexicographic
  if (tid < 32) {
    int c = scnt[tid]; if (c > 20) c = 20;
    if (c > 16) {
      for (int t = 0; t < 16; ++t) {
        int best = t;
        for (int u = t + 1; u < c; ++u) {
          float da = sd2[tid * 20 + u], db = sd2[tid * 20 + best];
          int ia = sidx[tid * 20 + u], ib = sidx[tid * 20 + best];
          if (da < db || (da == db && ia < ib)) best = u;
        }
        float td = sd2[tid * 20 + t]; sd2[tid * 20 + t] = sd2[tid * 20 + best]; sd2[tid * 20 + best] = td;
        int ti = sidx[tid * 20 + t]; sidx[tid * 20 + t] = sidx[tid * 20 + best]; sidx[tid * 20 + best] = ti;
      }
    }
  }
  __syncthreads();
  {
    int pp = tid >> 4, kk = tid & 15;        // 512 threads = 32 pts x 16 nbrs
    knn_out[((size_t)b * NPTS + chunk * CHUNK_PTS + pp) * KNB + kk] = sidx[pp * 20 + kk];
  }
}

// Fused edge-MLP + max. 16 lanes/point; neighbor-dependent 12x12 blocks only.
__global__ __launch_bounds__(256) void mlp_kernel(
    const float* __restrict__ pre, const float* __restrict__ aux,
    const int* __restrict__ knn, const float* __restrict__ x,
    const float* __restrict__ w2, const float* __restrict__ g2,
    const float* __restrict__ v2, const float* __restrict__ w3,
    float* __restrict__ out) {
  __shared__ float sW2h[144], sW3h2[144], sW3h1[144];
  __shared__ float sout[87 * 16];
  int tid = threadIdx.x;
  if (tid < 144) {
    int o = tid / 12, i = tid - o * 12;
    float inv2 = g2[o] / sqrtf(v2[o] + EPS);
    sW2h[tid]  = w2[o * 60 + i] * inv2;
    sW3h2[tid] = w3[o * 72 + i];
    sW3h1[tid] = w3[o * 72 + 12 + i];
  }
  __syncthreads();
  int k = tid & 15, pl = tid >> 4;
  int p = blockIdx.x * 16 + pl;            // 0..16383
  int b = p >> 11, n = p & (NPTS - 1);
  int nb = knn[(size_t)p * KNB + k];
  const float4* u4 = (const float4*)(aux + (size_t)p * 72);
  const float4* a4 = (const float4*)(aux + ((size_t)(b << 11) + nb) * 72 + 36);
  float uc[36], av[36];
#pragma unroll
  for (int i = 0; i < 9; ++i) {
    float4 t = u4[i];
    uc[4*i] = t.x; uc[4*i+1] = t.y; uc[4*i+2] = t.z; uc[4*i+3] = t.w;
    float4 t2 = a4[i];
    av[4*i] = t2.x; av[4*i+1] = t2.y; av[4*i+2] = t2.z; av[4*i+3] = t2.w;
  }
  float h1[12], h2[12], h3[12];
#pragma unroll
  for (int o = 0; o < 12; ++o) h1[o] = fmaxf(uc[o] + av[o], 0.f);
#pragma unroll
  for (int o = 0; o < 12; ++o) {
    float a = uc[12 + o] + av[12 + o];
#pragma unroll
    for (int i = 0; i < 12; ++i) a = fmaf(sW2h[o * 12 + i], h1[i], a);
    h2[o] = fmaxf(a, 0.f);
  }
#pragma unroll
  for (int o = 0; o < 12; ++o) {
    float a = uc[24 + o] + av[24 + o];
#pragma unroll
    for (int i = 0; i < 12; ++i) a = fmaf(sW3h2[o * 12 + i], h2[i], a);
#pragma unroll
    for (int i = 0; i < 12; ++i) a = fmaf(sW3h1[o * 12 + i], h1[i], a);
    h3[o] = a;
  }
  float nbf[24];
  const float4* pn4 = (const float4*)(pre + ((size_t)(b << 11) + nb) * 24);
#pragma unroll
  for (int i = 0; i < 6; ++i) {
    float4 t = pn4[i];
    nbf[4*i] = t.x; nbf[4*i+1] = t.y; nbf[4*i+2] = t.z; nbf[4*i+3] = t.w;
  }
#pragma unroll
  for (int m = 1; m < 16; m <<= 1) {
#pragma unroll
    for (int o = 0; o < 12; ++o) {
      h1[o] = fmaxf(h1[o], __shfl_xor(h1[o], m, 16));
      h2[o] = fmaxf(h2[o], __shfl_xor(h2[o], m, 16));
      h3[o] = fmaxf(h3[o], __shfl_xor(h3[o], m, 16));
    }
#pragma unroll
    for (int i = 0; i < 24; ++i)
      nbf[i] = fmaxf(nbf[i], __shfl_xor(nbf[i], m, 16));
  }
  if (k == 0) {
    const float4* c4 = (const float4*)(pre + (size_t)p * 24);
#pragma unroll
    for (int o = 0; o < 12; ++o) {
      sout[(0  + o) * 16 + pl] = h3[o];
      sout[(12 + o) * 16 + pl] = h2[o];
      sout[(24 + o) * 16 + pl] = h1[o];
    }
#pragma unroll
    for (int i = 0; i < 6; ++i) {
      float4 t = c4[i];
      sout[(36 + 4*i    ) * 16 + pl] = t.x;
      sout[(36 + 4*i + 1) * 16 + pl] = t.y;
      sout[(36 + 4*i + 2) * 16 + pl] = t.z;
      sout[(36 + 4*i + 3) * 16 + pl] = t.w;
    }
#pragma unroll
    for (int i = 0; i < 24; ++i) sout[(60 + i) * 16 + pl] = nbf[i];
    const float* xb = x + (size_t)b * 3 * NPTS + n;
    sout[84 * 16 + pl] = xb[0];
    sout[85 * 16 + pl] = xb[NPTS];
    sout[86 * 16 + pl] = xb[2 * NPTS];
  }
  __syncthreads();
  int n0 = (blockIdx.x * 16) & (NPTS - 1);
  float* ob = out + (size_t)b * 87 * NPTS;
  for (int j2 = tid; j2 < 87 * 16; j2 += 256) {
    int c = j2 >> 4, i = j2 & 15;
    ob[(size_t)c * NPTS + n0 + i] = sout[j2];
  }
}

extern "C" void kernel_launch(void* const* d_in, const int* in_sizes, int n_in,
                              void* d_out, int out_size, void* d_ws, size_t ws_size,
                              hipStream_t stream) {
  (void)in_sizes; (void)n_in; (void)out_size; (void)ws_size;
  const float* x     = (const float*)d_in[0];
  const float* w_pre = (const float*)d_in[1];
  const float* b_pre = (const float*)d_in[2];
  const float* g_pre = (const float*)d_in[3];
  const float* be_pre= (const float*)d_in[4];
  const float* m_pre = (const float*)d_in[5];
  const float* v_pre = (const float*)d_in[6];
  const float* w1    = (const float*)d_in[7];
  const float* g1    = (const float*)d_in[8];
  const float* be1   = (const float*)d_in[9];
  const float* m1    = (const float*)d_in[10];
  const float* v1    = (const float*)d_in[11];
  const float* w2    = (const float*)d_in[12];
  const float* g2    = (const float*)d_in[13];
  const float* be2   = (const float*)d_in[14];
  const float* m2    = (const float*)d_in[15];
  const float* v2    = (const float*)d_in[16];
  const float* w3    = (const float*)d_in[17];
  float* ws  = (float*)d_ws;
  float* pre = ws + WS_PRE;
  float* aux = ws + WS_AUX;
  int*   knn = (int*)(ws + WS_IDX);
  float4* c4g = (float4*)(ws + WS_C4G);
  float* out = (float*)d_out;

  prep_kernel<<<NBATCH * NPTS / 256, 256, 0, stream>>>(x, c4g);
  fused_kernel<<<KNN_BLKS, THREADS, FUSED_LDS, stream>>>(
      x, w_pre, b_pre, g_pre, be_pre, m_pre, v_pre,
      w1, g1, be1, m1, v1, w2, g2, be2, m2, v2, w3,
      c4g, pre, aux, knn);
  mlp_kernel<<<NBATCH * NPTS / 16, 256, 0, stream>>>(pre, aux, knn, x,
                                                     w2, g2, v2, w3, out);
}

// Round 9
// 153.183 us; speedup vs baseline: 1.3268x; 1.0463x over previous
//
#include <hip/hip_runtime.h>
#include <math.h>

#define EPS 1e-5f
#define NBATCH 8
#define NPTS 2048
#define KNB 16
#define BIG 3.2e38f

#define CHUNK_PTS 32
#define KNN_BLKS (NBATCH * 64)    // 64 chunks of 32 points per batch = 512 blocks
#define THREADS 512
#define FUSED_LDS 54400           // 32KB C4 + 16KB shared + 5.2KB tie bufs -> 2 blocks/CU

// ---- workspace layout (in floats) ----
#define WS_PRE 0                             // 16384*24
#define WS_AUX (16384 * 24)                  // 16384*72
#define WS_IDX (WS_AUX + 16384 * 72)         // 16384*16 ints

// C4 holds (-2x,-2y,-2z,sq); me* are RAW query coords (recovered exactly).
// MUST be bitwise identical in phase 1 (scan) and phase 3 (rescan).
__device__ __forceinline__ float dist2f(float mex, float mey, float mez,
                                        float sqn, float4 q) {
  return fmaf(mex, q.x, fmaf(mey, q.y, fmaf(mez, q.z, __fadd_rn(sqn, q.w))));
}

__device__ __forceinline__ void sort16(float S[16]) {
#pragma unroll
  for (int pw = 1; pw < 16; pw <<= 1) {
#pragma unroll
    for (int k = pw; k >= 1; k >>= 1) {
#pragma unroll
      for (int j = (k & (pw - 1)); j + k < 16; j += 2 * k) {
#pragma unroll
        for (int i = 0; i < k; ++i) {
          int a = i + j, bq = i + j + k;
          if (bq < 16 && (a / (2 * pw) == bq / (2 * pw))) {
            float lo = fminf(S[a], S[bq]);
            float hi = fmaxf(S[a], S[bq]);
            S[a] = lo; S[bq] = hi;
          }
        }
      }
    }
  }
}

__device__ __forceinline__ void clean16(float m[16]) {
#pragma unroll
  for (int d = 8; d >= 1; d >>= 1) {
#pragma unroll
    for (int i = 0; i < 16; ++i) {
      if (!(i & d)) {
        float lo = fminf(m[i], m[i | d]);
        float hi = fmaxf(m[i], m[i | d]);
        m[i] = lo; m[i | d] = hi;
      }
    }
  }
}

// keep-16-smallest of sorted L and sorted S (bitonic lower half)
__device__ __forceinline__ void merge16(float L[16], const float S[16]) {
  float m[16];
#pragma unroll
  for (int i = 0; i < 16; ++i) m[i] = fminf(L[i], S[15 - i]);
  clean16(m);
#pragma unroll
  for (int i = 0; i < 16; ++i) L[i] = m[i];
}

// Load + distance for one 16-candidate batch (issues 16 ds_read_b128).
template <bool HASSELF>
__device__ __forceinline__ void dist_batch(const float4* __restrict__ Cs, int c0,
                                           int selfc, float mex, float mey,
                                           float mez, float sqn, float S[16]) {
#pragma unroll
  for (int cc = 0; cc < 16; ++cc) {
    float4 q = Cs[c0 + cc];
    float d2 = dist2f(mex, mey, mez, sqn, q);
    if (HASSELF) S[cc] = ((c0 + cc) == selfc) ? BIG : d2;
    else         S[cc] = d2;
  }
}

// Phase-1 scan of one 128-candidate slice, software-pipelined:
// batch t+1's loads/distances issue before batch t's sort network, so the
// ds_read latency hides under the VALU-dense sort (hand-unrolled: rule #20).
template <bool HASSELF>
__device__ __forceinline__ void scan_slice(const float4* __restrict__ Cs, int selfc,
                                           float mex, float mey, float mez,
                                           float sqn, float L[16]) {
  float Sa[16], Sb[16];
  dist_batch<HASSELF>(Cs,   0, selfc, mex, mey, mez, sqn, Sa);
  dist_batch<HASSELF>(Cs,  16, selfc, mex, mey, mez, sqn, Sb);
  sort16(Sa); merge16(L, Sa);
  dist_batch<HASSELF>(Cs,  32, selfc, mex, mey, mez, sqn, Sa);
  sort16(Sb); merge16(L, Sb);
  dist_batch<HASSELF>(Cs,  48, selfc, mex, mey, mez, sqn, Sb);
  sort16(Sa); merge16(L, Sa);
  dist_batch<HASSELF>(Cs,  64, selfc, mex, mey, mez, sqn, Sa);
  sort16(Sb); merge16(L, Sb);
  dist_batch<HASSELF>(Cs,  80, selfc, mex, mey, mez, sqn, Sb);
  sort16(Sa); merge16(L, Sa);
  dist_batch<HASSELF>(Cs,  96, selfc, mex, mey, mez, sqn, Sa);
  sort16(Sb); merge16(L, Sb);
  dist_batch<HASSELF>(Cs, 112, selfc, mex, mey, mez, sqn, Sb);
  sort16(Sa); merge16(L, Sa);
  sort16(Sb); merge16(L, Sb);
}

// One uniform kernel: every block handles 32 points: pre+aux fold + exact 16-NN.
// 512 threads = 8 waves; each wave holds 2 slices of 128 (2-way broadcast = free).
__global__ __launch_bounds__(THREADS, 4) void fused_kernel(
    const float* __restrict__ x,
    const float* __restrict__ w_pre, const float* __restrict__ b_pre,
    const float* __restrict__ g_pre, const float* __restrict__ be_pre,
    const float* __restrict__ m_pre, const float* __restrict__ v_pre,
    const float* __restrict__ w1, const float* __restrict__ g1,
    const float* __restrict__ be1, const float* __restrict__ m1,
    const float* __restrict__ v1,
    const float* __restrict__ w2, const float* __restrict__ g2,
    const float* __restrict__ be2, const float* __restrict__ m2,
    const float* __restrict__ v2, const float* __restrict__ w3,
    float* __restrict__ pre, float* __restrict__ aux,
    int* __restrict__ knn_out) {
  extern __shared__ char smem[];
  float4* C4   = (float4*)smem;              // [2048] (-2x,-2y,-2z,sq), 32 KB
  float* slist = (float*)(smem + 32768);     // 4096 floats, 16 KB, time-shared:
  // life 1 (until Step-B barrier): folded weights, transposed for bank-free reads
  float* fwp   = slist;                      // 72   [o*3+c]
  float* fbp   = fwp + 72;                   // 24
  float* fw1t  = fbp + 24;                   // 576  [i*12+o] = w1[o*48+i]*inv1
  float* fb1   = fw1t + 576;                 // 12
  float* fw2t  = fb1 + 12;                   // 720  [i*12+o] = w2[o*60+i]*inv2
  float* fb2   = fw2t + 720;                 // 12
  float* fw3t  = fb2 + 12;                   // 576  [i*12+o] = w3[o*72+24+i]
  float* sinv1 = fw3t + 576;                 // 12
  float* sinv2 = sinv1 + 12;                 // 12
  float* sinvP = sinv2 + 12;                 // 24  (total 2040)
  // life 2 (phase 1/2): merge lists [8 lists][16 vals][32 pts] = 4096 floats
  // dedicated tie buffers (zeroed in Step A; rescan can start right after tau)
  float* sd2  = (float*)(smem + 49152);      // [32][20], 2560 B
  int*   sidx = (int*)(smem + 51712);        // [32][20], 2560 B
  int*   scnt = (int*)(smem + 54272);        // [32], 128 B

  int tid = threadIdx.x;
  int bi = blockIdx.x;
  int b = bi >> 6, chunk = bi & 63;
  const float* xb = x + (size_t)b * 3 * NPTS;

  // ---- Step A: build C4 (negated-doubled coords), zero tie bufs, BN inverses ----
  for (int j = tid; j < NPTS; j += THREADS) {
    float xx = xb[j], yy = xb[NPTS + j], zz = xb[2 * NPTS + j];
    float sq = __fadd_rn(__fadd_rn(__fmul_rn(xx, xx), __fmul_rn(yy, yy)),
                         __fmul_rn(zz, zz));
    C4[j] = make_float4(-2.0f * xx, -2.0f * yy, -2.0f * zz, sq);
  }
  for (int j = tid; j < 32 * 20; j += THREADS) sidx[j] = 0;
  if (tid < 32) scnt[tid] = 0;
  if (tid < 24) sinvP[tid] = g_pre[tid] / sqrtf(v_pre[tid] + EPS);
  if (tid < 12) { sinv1[tid] = g1[tid] / sqrtf(v1[tid] + EPS);
                  sinv2[tid] = g2[tid] / sqrtf(v2[tid] + EPS); }
  __syncthreads();
  if (tid < 72) fwp[tid] = w_pre[tid] * sinvP[tid / 3];
  if (tid < 24) fbp[tid] = (b_pre[tid] - m_pre[tid]) * sinvP[tid] + be_pre[tid];
  if (tid < 12) { fb1[tid] = be1[tid] - m1[tid] * sinv1[tid];
                  fb2[tid] = be2[tid] - m2[tid] * sinv2[tid]; }
  for (int j = tid; j < 576; j += THREADS) { int i = j / 12, o = j - i * 12; fw1t[j] = w1[o * 48 + i] * sinv1[o]; }
  for (int j = tid; j < 720; j += THREADS) { int i = j / 12, o = j - i * 12; fw2t[j] = w2[o * 60 + i] * sinv2[o]; }
  for (int j = tid; j < 576; j += THREADS) { int i = j / 12, o = j - i * 12; fw3t[j] = w3[o * 72 + 24 + i]; }
  __syncthreads();

  // ---- Step B: pre + aux for this block's 32 points (16 lanes/point) ----
  {
    int r = tid & 15, pt = tid >> 4;
    int n0 = chunk * CHUNK_PTS + pt;
    size_t pgl = (size_t)(b << 11) + n0;
    float x0 = xb[n0], x1 = xb[NPTS + n0], x2 = xb[2 * NPTS + n0];
    float pr[24];
#pragma unroll
    for (int c = 0; c < 24; ++c) {
      float v = fmaf(fwp[c * 3 + 0], x0,
                fmaf(fwp[c * 3 + 1], x1,
                fmaf(fwp[c * 3 + 2], x2, fbp[c])));
      pr[c] = fmaxf(v, 0.f);
    }
    if (r == 12) {   // pre writer on a lane disjoint from aux lanes
      float4* o4 = (float4*)(pre + pgl * 24);
#pragma unroll
      for (int i = 0; i < 6; ++i)
        o4[i] = make_float4(pr[4*i], pr[4*i+1], pr[4*i+2], pr[4*i+3]);
    }
    if (r < 12) {
      int o = r;
      float u1 = fb1[o], a1 = 0.f, u2 = fb2[o], a2 = 0.f, u3 = 0.f, a3 = 0.f;
#pragma unroll
      for (int i = 0; i < 24; ++i) {
        u1 = fmaf(fw1t[i * 12 + o],        pr[i], u1);
        a1 = fmaf(fw1t[(24 + i) * 12 + o], pr[i], a1);
        u2 = fmaf(fw2t[(12 + i) * 12 + o], pr[i], u2);
        a2 = fmaf(fw2t[(36 + i) * 12 + o], pr[i], a2);
        u3 = fmaf(fw3t[i * 12 + o],        pr[i], u3);
        a3 = fmaf(fw3t[(24 + i) * 12 + o], pr[i], a3);
      }
      float* A = aux + pgl * 72;
      A[o] = u1; A[12 + o] = u2; A[24 + o] = u3;
      A[36 + o] = a1; A[48 + o] = a2; A[60 + o] = a3;
    }
  }
  __syncthreads();   // folded-weight area dead; slist lists live from here

  // ---- Step C: exact 16-NN, 32 points x 16 slices of 128 candidates ----
  int p = tid & 31, s = tid >> 5;            // point 0..31, slice 0..15
  int w = tid >> 6;                          // wave 0..7 (slices 2w, 2w+1)
  int n = chunk * CHUNK_PTS + p;
  float4 me4 = C4[n];
  float mex = -0.5f * me4.x, mey = -0.5f * me4.y, mez = -0.5f * me4.z;
  float sqn = me4.w;
  const float4* Cs = C4 + s * 128;
  int selfc = n - s * 128;                   // in [0,128) only for self slice
  int wself = chunk >> 3;                    // wave whose slice pair holds self
  // Phase 1: pipelined batched top-16; self mask only in the self wave
  float L[16];
#pragma unroll
  for (int t = 0; t < 16; ++t) L[t] = BIG;
  if (w == wself) scan_slice<true >(Cs, selfc, mex, mey, mez, sqn, L);
  else            scan_slice<false>(Cs, selfc, mex, mey, mez, sqn, L);
  // in-wave merge: the wave's two slices (lanes l and l^32 share point p)
  {
    float bb[16], m16[16];
#pragma unroll
    for (int i = 0; i < 16; ++i) bb[i] = __shfl_xor(L[i], 32, 64);
#pragma unroll
    for (int i = 0; i < 16; ++i) m16[i] = fminf(L[i], bb[15 - i]);
    clean16(m16);
    if (!(s & 1)) {                          // lanes 0..31 of each wave
#pragma unroll
      for (int i = 0; i < 16; ++i) slist[(w * 16 + i) * 32 + p] = m16[i];
    }
  }
  __syncthreads();
  // Phase 2: merge tree 8 -> 4 -> 2 -> 1 lists (parallel over points)
  for (int W = 4; W >= 1; W >>= 1) {
    int u = tid >> 5;
    bool act = (u < W);
    float a[16], bb[16];
    if (act) {
#pragma unroll
      for (int i = 0; i < 16; ++i) a[i]  = slist[((2 * u) * 16 + i) * 32 + p];
#pragma unroll
      for (int i = 0; i < 16; ++i) bb[i] = slist[((2 * u + 1) * 16 + i) * 32 + p];
    }
    __syncthreads();
    if (act) {
      float m16[16];
#pragma unroll
      for (int i = 0; i < 16; ++i) m16[i] = fminf(a[i], bb[15 - i]);
      clean16(m16);
#pragma unroll
      for (int i = 0; i < 16; ++i) slist[(u * 16 + i) * 32 + p] = m16[i];
    }
    __syncthreads();
  }
  float tau = slist[15 * 32 + p];            // exact 16th smallest (self excluded)
  // Phase 3: rescan own slice immediately (tie bufs are dedicated + pre-zeroed;
  // writes don't touch slist, other waves only read their own slist word).
  if (w == wself) {
#pragma unroll 4
    for (int c = 0; c < 128; ++c) {
      float4 q = Cs[c];
      float d2 = dist2f(mex, mey, mez, sqn, q);
      int j = s * 128 + c;
      if (d2 <= tau && j != n) {
        int pos = atomicAdd(&scnt[p], 1);
        if (pos < 20) { sd2[p * 20 + pos] = d2; sidx[p * 20 + pos] = j; }
      }
    }
  } else {
#pragma unroll 4
    for (int c = 0; c < 128; ++c) {
      float4 q = Cs[c];
      float d2 = dist2f(mex, mey, mez, sqn, q);
      int j = s * 128 + c;
      if (d2 <= tau) {
        int pos = atomicAdd(&scnt[p], 1);
        if (pos < 20) { sd2[p * 20 + pos] = d2; sidx[p * 20 + pos] = j; }
      }
    }
  }
  __syncthreads();
  // Phase 4: rare tie fixup — keep 16 smallest by (d2, idx) lexicographic
  if (tid < 32) {
    int c = scnt[tid]; if (c > 20) c = 20;
    if (c > 16) {
      for (int t = 0; t < 16; ++t) {
        int best = t;
        for (int u = t + 1; u < c; ++u) {
          float da = sd2[tid * 20 + u], db = sd2[tid * 20 + best];
          int ia = sidx[tid * 20 + u], ib = sidx[tid * 20 + best];
          if (da < db || (da == db && ia < ib)) best = u;
        }
        float td = sd2[tid * 20 + t]; sd2[tid * 20 + t] = sd2[tid * 20 + best]; sd2[tid * 20 + best] = td;
        int ti = sidx[tid * 20 + t]; sidx[tid * 20 + t] = sidx[tid * 20 + best]; sidx[tid * 20 + best] = ti;
      }
    }
  }
  __syncthreads();
  {
    int pp = tid >> 4, kk = tid & 15;        // 512 threads = 32 pts x 16 nbrs
    knn_out[((size_t)b * NPTS + chunk * CHUNK_PTS + pp) * KNB + kk] = sidx[pp * 20 + kk];
  }
}

// Fused edge-MLP + max. 16 lanes/point; neighbor-dependent 12x12 blocks only.
__global__ __launch_bounds__(256) void mlp_kernel(
    const float* __restrict__ pre, const float* __restrict__ aux,
    const int* __restrict__ knn, const float* __restrict__ x,
    const float* __restrict__ w2, const float* __restrict__ g2,
    const float* __restrict__ v2, const float* __restrict__ w3,
    float* __restrict__ out) {
  __shared__ float sW2h[144], sW3h2[144], sW3h1[144];
  __shared__ float sout[87 * 16];
  int tid = threadIdx.x;
  if (tid < 144) {
    int o = tid / 12, i = tid - o * 12;
    float inv2 = g2[o] / sqrtf(v2[o] + EPS);
    sW2h[tid]  = w2[o * 60 + i] * inv2;
    sW3h2[tid] = w3[o * 72 + i];
    sW3h1[tid] = w3[o * 72 + 12 + i];
  }
  __syncthreads();
  int k = tid & 15, pl = tid >> 4;
  int p = blockIdx.x * 16 + pl;            // 0..16383
  int b = p >> 11, n = p & (NPTS - 1);
  int nb = knn[(size_t)p * KNB + k];
  const float4* u4 = (const float4*)(aux + (size_t)p * 72);
  const float4* a4 = (const float4*)(aux + ((size_t)(b << 11) + nb) * 72 + 36);
  float uc[36], av[36];
#pragma unroll
  for (int i = 0; i < 9; ++i) {
    float4 t = u4[i];
    uc[4*i] = t.x; uc[4*i+1] = t.y; uc[4*i+2] = t.z; uc[4*i+3] = t.w;
    float4 t2 = a4[i];
    av[4*i] = t2.x; av[4*i+1] = t2.y; av[4*i+2] = t2.z; av[4*i+3] = t2.w;
  }
  float h1[12], h2[12], h3[12];
#pragma unroll
  for (int o = 0; o < 12; ++o) h1[o] = fmaxf(uc[o] + av[o], 0.f);
#pragma unroll
  for (int o = 0; o < 12; ++o) {
    float a = uc[12 + o] + av[12 + o];
#pragma unroll
    for (int i = 0; i < 12; ++i) a = fmaf(sW2h[o * 12 + i], h1[i], a);
    h2[o] = fmaxf(a, 0.f);
  }
#pragma unroll
  for (int o = 0; o < 12; ++o) {
    float a = uc[24 + o] + av[24 + o];
#pragma unroll
    for (int i = 0; i < 12; ++i) a = fmaf(sW3h2[o * 12 + i], h2[i], a);
#pragma unroll
    for (int i = 0; i < 12; ++i) a = fmaf(sW3h1[o * 12 + i], h1[i], a);
    h3[o] = a;
  }
  float nbf[24];
  const float4* pn4 = (const float4*)(pre + ((size_t)(b << 11) + nb) * 24);
#pragma unroll
  for (int i = 0; i < 6; ++i) {
    float4 t = pn4[i];
    nbf[4*i] = t.x; nbf[4*i+1] = t.y; nbf[4*i+2] = t.z; nbf[4*i+3] = t.w;
  }
#pragma unroll
  for (int m = 1; m < 16; m <<= 1) {
#pragma unroll
    for (int o = 0; o < 12; ++o) {
      h1[o] = fmaxf(h1[o], __shfl_xor(h1[o], m, 16));
      h2[o] = fmaxf(h2[o], __shfl_xor(h2[o], m, 16));
      h3[o] = fmaxf(h3[o], __shfl_xor(h3[o], m, 16));
    }
#pragma unroll
    for (int i = 0; i < 24; ++i)
      nbf[i] = fmaxf(nbf[i], __shfl_xor(nbf[i], m, 16));
  }
  if (k == 0) {
    const float4* c4 = (const float4*)(pre + (size_t)p * 24);
#pragma unroll
    for (int o = 0; o < 12; ++o) {
      sout[(0  + o) * 16 + pl] = h3[o];
      sout[(12 + o) * 16 + pl] = h2[o];
      sout[(24 + o) * 16 + pl] = h1[o];
    }
#pragma unroll
    for (int i = 0; i < 6; ++i) {
      float4 t = c4[i];
      sout[(36 + 4*i    ) * 16 + pl] = t.x;
      sout[(36 + 4*i + 1) * 16 + pl] = t.y;
      sout[(36 + 4*i + 2) * 16 + pl] = t.z;
      sout[(36 + 4*i + 3) * 16 + pl] = t.w;
    }
#pragma unroll
    for (int i = 0; i < 24; ++i) sout[(60 + i) * 16 + pl] = nbf[i];
    const float* xb = x + (size_t)b * 3 * NPTS + n;
    sout[84 * 16 + pl] = xb[0];
    sout[85 * 16 + pl] = xb[NPTS];
    sout[86 * 16 + pl] = xb[2 * NPTS];
  }
  __syncthreads();
  int n0 = (blockIdx.x * 16) & (NPTS - 1);
  float* ob = out + (size_t)b * 87 * NPTS;
  for (int j2 = tid; j2 < 87 * 16; j2 += 256) {
    int c = j2 >> 4, i = j2 & 15;
    ob[(size_t)c * NPTS + n0 + i] = sout[j2];
  }
}

extern "C" void kernel_launch(void* const* d_in, const int* in_sizes, int n_in,
                              void* d_out, int out_size, void* d_ws, size_t ws_size,
                              hipStream_t stream) {
  (void)in_sizes; (void)n_in; (void)out_size; (void)ws_size;
  const float* x     = (const float*)d_in[0];
  const float* w_pre = (const float*)d_in[1];
  const float* b_pre = (const float*)d_in[2];
  const float* g_pre = (const float*)d_in[3];
  const float* be_pre= (const float*)d_in[4];
  const float* m_pre = (const float*)d_in[5];
  const float* v_pre = (const float*)d_in[6];
  const float* w1    = (const float*)d_in[7];
  const float* g1    = (const float*)d_in[8];
  const float* be1   = (const float*)d_in[9];
  const float* m1    = (const float*)d_in[10];
  const float* v1    = (const float*)d_in[11];
  const float* w2    = (const float*)d_in[12];
  const float* g2    = (const float*)d_in[13];
  const float* be2   = (const float*)d_in[14];
  const float* m2    = (const float*)d_in[15];
  const float* v2    = (const float*)d_in[16];
  const float* w3    = (const float*)d_in[17];
  float* ws  = (float*)d_ws;
  float* pre = ws + WS_PRE;
  float* aux = ws + WS_AUX;
  int*   knn = (int*)(ws + WS_IDX);
  float* out = (float*)d_out;

  fused_kernel<<<KNN_BLKS, THREADS, FUSED_LDS, stream>>>(
      x, w_pre, b_pre, g_pre, be_pre, m_pre, v_pre,
      w1, g1, be1, m1, v1, w2, g2, be2, m2, v2, w3,
      pre, aux, knn);
  mlp_kernel<<<NBATCH * NPTS / 16, 256, 0, stream>>>(pre, aux, knn, x,
                                                     w2, g2, v2, w3, out);
}